// Round 10
// baseline (35.450 us; speedup 1.0000x reference)
//
#include <hip/hip_runtime.h>

#ifndef FLT_MAX
#define FLT_MAX 3.402823466e+38f
#endif

typedef float v2f __attribute__((ext_vector_type(2)));
typedef float v4f __attribute__((ext_vector_type(4)));

__device__ __forceinline__ float sel3(int i, float a, float b, float c) {
    return i == 0 ? a : (i == 1 ? b : c);
}

__device__ __forceinline__ float sel4(int i, float a, float b, float c, float d) {
    return i == 0 ? a : (i == 1 ? b : (i == 2 ? c : d));
}

// Deterministic d2 (scalar), element-wise identical to packed pipeline below.
__device__ __forceinline__ float d2f(float ax, float ay, float az,
                                     float bx, float by, float bz) {
    const float dx = __fsub_rn(ax, bx);
    const float dy = __fsub_rn(ay, by);
    const float dz = __fsub_rn(az, bz);
    return __builtin_fmaf(dx, dx, __builtin_fmaf(dy, dy, __fmul_rn(dz, dz)));
}

__device__ __forceinline__ v2f d2p(v2f ax, v2f ay, v2f az, v2f bx, v2f by, v2f bz) {
    const v2f dx = ax - bx, dy = ay - by, dz = az - bz;
    return __builtin_elementwise_fma(dx, dx,
           __builtin_elementwise_fma(dy, dy, dz * dz));
}

// ---------- Kernel 1: gather-once cluster coords table -----------------------
// T[c] = SoA [3][64] f32 (stride 192 floats = 768B). One wave per cluster:
// lane p gathers data[clusts[c][p]] once; 3 coalesced component stores.
__global__ __launch_bounds__(256) void build_table_kernel(
    const float* __restrict__ data,
    const int*   __restrict__ clusts,
    float*       __restrict__ T,
    int C)
{
    const int c = blockIdx.x * 4 + (threadIdx.x >> 6);
    const int p = threadIdx.x & 63;
    if (c >= C) return;
    const int pid = clusts[c * 64 + p];
    const float4 d = *reinterpret_cast<const float4*>(data + (size_t)pid * 4);
    float* row = T + (size_t)c * 192;
    row[p]       = d.y;
    row[p + 64]  = d.z;
    row[p + 128] = d.w;
}

// ---------- Kernel 2: scan (R9 structure, dense coalesced prologue) ----------
// FOUR edges per 64-lane wave; 16-lane group n owns edge n. Lane 16n+t owns
// rows 4t..4t+3 of x1 and cols 4t..4t+3 of x2, loaded as 6 coalesced b128
// reads from T (no random per-edge gather). Per-edge LDS slice padded to 196
// floats; value-only packed scan; bit-exact register recompute (numpy argmin).
#define SLICE 196

__global__ __launch_bounds__(256, 4) void clustgeo_scan_kernel(
    const float* __restrict__ T,       // (C,3,64) f32 dense table
    const int*   __restrict__ eidx,    // (2,E)  int
    float*       __restrict__ out,     // (E,19) f32
    int E)
{
    const int wave = threadIdx.x >> 6;
    const int lane = threadIdx.x & 63;
    const int t    = lane & 15;
    const int gsh  = lane & 48;
    const int e    = blockIdx.x * 16 + wave * 4 + (lane >> 4);
    const int ec   = e < E ? e : (E - 1);

    __shared__ __align__(16) float sx[4][4][SLICE];

    const int ca = eidx[ec];
    const int cb = eidx[E + ec];
    const float* Ta = T + (size_t)ca * 192;
    const float* Tb = T + (size_t)cb * 192;

    // x1 rows 4t..4t+3 (coalesced within the group).
    const v4f RX = *reinterpret_cast<const v4f*>(Ta + 4 * t);
    const v4f RY = *reinterpret_cast<const v4f*>(Ta + 64 + 4 * t);
    const v4f RZ = *reinterpret_cast<const v4f*>(Ta + 128 + 4 * t);
    // x2 cols 4t..4t+3 (kept in regs for phase 2; also staged to LDS).
    const v4f CX = *reinterpret_cast<const v4f*>(Tb + 4 * t);
    const v4f CY = *reinterpret_cast<const v4f*>(Tb + 64 + 4 * t);
    const v4f CZ = *reinterpret_cast<const v4f*>(Tb + 128 + 4 * t);

    float* slice = &sx[wave][lane >> 4][0];
    *reinterpret_cast<v4f*>(slice + 4 * t)       = CX;
    *reinterpret_cast<v4f*>(slice + 64 + 4 * t)  = CY;
    *reinterpret_cast<v4f*>(slice + 128 + 4 * t) = CZ;
    // No barrier: each group reads only its own slice; same-wave LDS RAW is
    // ordered by compiler-inserted lgkmcnt waits (validated R3-R9).

    const float r0x=RX.x, r1x=RX.y, r2x=RX.z, r3x=RX.w;
    const float r0y=RY.x, r1y=RY.y, r2y=RY.z, r3y=RY.w;
    const float r0z=RZ.x, r1z=RZ.y, r2z=RZ.z, r3z=RZ.w;

    const v4f* SL = reinterpret_cast<const v4f*>(slice);   // [c*16 + g]

    v2f a0 = {FLT_MAX, FLT_MAX}, a1 = {FLT_MAX, FLT_MAX};
    v2f a2 = {FLT_MAX, FLT_MAX}, a3 = {FLT_MAX, FLT_MAX};
    #pragma unroll 2
    for (int g = 0; g < 16; ++g) {
        const v4f X = SL[g];
        const v4f Y = SL[16 + g];
        const v4f Z = SL[32 + g];
        const v2f xlo = X.xy, xhi = X.zw, ylo = Y.xy, yhi = Y.zw, zlo = Z.xy, zhi = Z.zw;
        a0 = __builtin_elementwise_min(a0, d2p((v2f){r0x,r0x},(v2f){r0y,r0y},(v2f){r0z,r0z}, xlo, ylo, zlo));
        a0 = __builtin_elementwise_min(a0, d2p((v2f){r0x,r0x},(v2f){r0y,r0y},(v2f){r0z,r0z}, xhi, yhi, zhi));
        a1 = __builtin_elementwise_min(a1, d2p((v2f){r1x,r1x},(v2f){r1y,r1y},(v2f){r1z,r1z}, xlo, ylo, zlo));
        a1 = __builtin_elementwise_min(a1, d2p((v2f){r1x,r1x},(v2f){r1y,r1y},(v2f){r1z,r1z}, xhi, yhi, zhi));
        a2 = __builtin_elementwise_min(a2, d2p((v2f){r2x,r2x},(v2f){r2y,r2y},(v2f){r2z,r2z}, xlo, ylo, zlo));
        a2 = __builtin_elementwise_min(a2, d2p((v2f){r2x,r2x},(v2f){r2y,r2y},(v2f){r2z,r2z}, xhi, yhi, zhi));
        a3 = __builtin_elementwise_min(a3, d2p((v2f){r3x,r3x},(v2f){r3y,r3y},(v2f){r3z,r3z}, xlo, ylo, zlo));
        a3 = __builtin_elementwise_min(a3, d2p((v2f){r3x,r3x},(v2f){r3y,r3y},(v2f){r3z,r3z}, xhi, yhi, zhi));
    }
    const float m0 = fminf(a0.x, a0.y);
    const float m1 = fminf(a1.x, a1.y);
    const float m2 = fminf(a2.x, a2.y);
    const float m3 = fminf(a3.x, a3.y);

    float bmn = fminf(fminf(m0, m1), fminf(m2, m3));
    #pragma unroll
    for (int off = 8; off; off >>= 1) bmn = fminf(bmn, __shfl_xor(bmn, off, 64));

    // First row attaining min. Row = 4t + r: lexicographic (t, r).
    const unsigned g0 = (unsigned)(__ballot(m0 == bmn) >> gsh) & 0xFFFFu;
    const unsigned g1 = (unsigned)(__ballot(m1 == bmn) >> gsh) & 0xFFFFu;
    const unsigned g2 = (unsigned)(__ballot(m2 == bmn) >> gsh) & 0xFFFFu;
    const unsigned g3 = (unsigned)(__ballot(m3 == bmn) >> gsh) & 0xFFFFu;
    const int t1 = __builtin_ctz(g0 | g1 | g2 | g3);
    const int s1 = (g0 >> t1) & 1 ? 0 : (g1 >> t1) & 1 ? 1 : (g2 >> t1) & 1 ? 2 : 3;

    const float v1x = __shfl(sel4(s1, RX.x, RX.y, RX.z, RX.w), gsh + t1, 64);
    const float v1y = __shfl(sel4(s1, RY.x, RY.y, RY.z, RY.w), gsh + t1, 64);
    const float v1z = __shfl(sel4(s1, RZ.x, RZ.y, RZ.z, RZ.w), gsh + t1, 64);

    // Phase 2: recompute row i1 over this lane's 4 register-held cols.
    const float d0 = d2f(v1x, v1y, v1z, CX.x, CY.x, CZ.x);
    const float d1 = d2f(v1x, v1y, v1z, CX.y, CY.y, CZ.y);
    const float d2_ = d2f(v1x, v1y, v1z, CX.z, CY.z, CZ.z);
    const float d3 = d2f(v1x, v1y, v1z, CX.w, CY.w, CZ.w);
    const unsigned h0 = (unsigned)(__ballot(d0 == bmn) >> gsh) & 0xFFFFu;
    const unsigned h1 = (unsigned)(__ballot(d1 == bmn) >> gsh) & 0xFFFFu;
    const unsigned h2 = (unsigned)(__ballot(d2_ == bmn) >> gsh) & 0xFFFFu;
    const unsigned h3 = (unsigned)(__ballot(d3 == bmn) >> gsh) & 0xFFFFu;
    const int t2 = __builtin_ctz(h0 | h1 | h2 | h3);
    const int s2 = (h0 >> t2) & 1 ? 0 : (h1 >> t2) & 1 ? 1 : (h2 >> t2) & 1 ? 2 : 3;

    const float v2x = __shfl(sel4(s2, CX.x, CX.y, CX.z, CX.w), gsh + t2, 64);
    const float v2y = __shfl(sel4(s2, CY.x, CY.y, CY.z, CY.w), gsh + t2, 64);
    const float v2z = __shfl(sel4(s2, CZ.x, CZ.y, CZ.z, CZ.w), gsh + t2, 64);

    float dx = v1x - v2x, dy = v1y - v2y, dz = v1z - v2z;
    const float lend = sqrtf(dx * dx + dy * dy + dz * dz);
    if (lend > 0.f) { dx /= lend; dy /= lend; dz /= lend; }

    if (e < E) {
        float* orow = out + (size_t)e * 19;
        float o;
        if (t < 3)       o = sel3(t,     v1x, v1y, v1z);
        else if (t < 6)  o = sel3(t - 3, v2x, v2y, v2z);
        else if (t < 9)  o = sel3(t - 6, dx, dy, dz);
        else if (t == 9) o = lend;
        else {
            const int k = t - 10;
            o = sel3(k / 3, dx, dy, dz) * sel3(k % 3, dx, dy, dz);
        }
        orow[t] = o;
        if (t < 3) {
            const int k = t + 6;   // elements 16,17,18 = B[6..8]
            orow[16 + t] = sel3(k / 3, dx, dy, dz) * sel3(k % 3, dx, dy, dz);
        }
    }
}

// ---------- Fallback (R9 kernel, gathers per edge; used if ws too small) -----
__global__ __launch_bounds__(256, 4) void clustgeo_edge_fallback(
    const float* __restrict__ data,
    const int*   __restrict__ clusts,
    const int*   __restrict__ eidx,
    float*       __restrict__ out,
    int E)
{
    const int wave = threadIdx.x >> 6;
    const int lane = threadIdx.x & 63;
    const int t    = lane & 15;
    const int gsh  = lane & 48;
    const int e    = blockIdx.x * 16 + wave * 4 + (lane >> 4);
    const int ec   = e < E ? e : (E - 1);

    __shared__ __align__(16) float sx[4][4][SLICE];

    const int ca = eidx[ec];
    const int cb = eidx[E + ec];
    const int4 P1 = *reinterpret_cast<const int4*>(clusts + ca * 64 + 4 * t);
    const int4 P2 = *reinterpret_cast<const int4*>(clusts + cb * 64 + 4 * t);
    const float4 q10 = *reinterpret_cast<const float4*>(data + (size_t)P1.x * 4);
    const float4 q11 = *reinterpret_cast<const float4*>(data + (size_t)P1.y * 4);
    const float4 q12 = *reinterpret_cast<const float4*>(data + (size_t)P1.z * 4);
    const float4 q13 = *reinterpret_cast<const float4*>(data + (size_t)P1.w * 4);
    const float4 q20 = *reinterpret_cast<const float4*>(data + (size_t)P2.x * 4);
    const float4 q21 = *reinterpret_cast<const float4*>(data + (size_t)P2.y * 4);
    const float4 q22 = *reinterpret_cast<const float4*>(data + (size_t)P2.z * 4);
    const float4 q23 = *reinterpret_cast<const float4*>(data + (size_t)P2.w * 4);
    const v4f RX = {q10.y, q11.y, q12.y, q13.y};
    const v4f RY = {q10.z, q11.z, q12.z, q13.z};
    const v4f RZ = {q10.w, q11.w, q12.w, q13.w};
    const v4f CX = {q20.y, q21.y, q22.y, q23.y};
    const v4f CY = {q20.z, q21.z, q22.z, q23.z};
    const v4f CZ = {q20.w, q21.w, q22.w, q23.w};

    float* slice = &sx[wave][lane >> 4][0];
    *reinterpret_cast<v4f*>(slice + 4 * t)       = CX;
    *reinterpret_cast<v4f*>(slice + 64 + 4 * t)  = CY;
    *reinterpret_cast<v4f*>(slice + 128 + 4 * t) = CZ;

    const v4f* SL = reinterpret_cast<const v4f*>(slice);
    v2f a0 = {FLT_MAX, FLT_MAX}, a1 = {FLT_MAX, FLT_MAX};
    v2f a2 = {FLT_MAX, FLT_MAX}, a3 = {FLT_MAX, FLT_MAX};
    #pragma unroll 2
    for (int g = 0; g < 16; ++g) {
        const v4f X = SL[g];
        const v4f Y = SL[16 + g];
        const v4f Z = SL[32 + g];
        const v2f xlo = X.xy, xhi = X.zw, ylo = Y.xy, yhi = Y.zw, zlo = Z.xy, zhi = Z.zw;
        a0 = __builtin_elementwise_min(a0, d2p((v2f){RX.x,RX.x},(v2f){RY.x,RY.x},(v2f){RZ.x,RZ.x}, xlo, ylo, zlo));
        a0 = __builtin_elementwise_min(a0, d2p((v2f){RX.x,RX.x},(v2f){RY.x,RY.x},(v2f){RZ.x,RZ.x}, xhi, yhi, zhi));
        a1 = __builtin_elementwise_min(a1, d2p((v2f){RX.y,RX.y},(v2f){RY.y,RY.y},(v2f){RZ.y,RZ.y}, xlo, ylo, zlo));
        a1 = __builtin_elementwise_min(a1, d2p((v2f){RX.y,RX.y},(v2f){RY.y,RY.y},(v2f){RZ.y,RZ.y}, xhi, yhi, zhi));
        a2 = __builtin_elementwise_min(a2, d2p((v2f){RX.z,RX.z},(v2f){RY.z,RY.z},(v2f){RZ.z,RZ.z}, xlo, ylo, zlo));
        a2 = __builtin_elementwise_min(a2, d2p((v2f){RX.z,RX.z},(v2f){RY.z,RY.z},(v2f){RZ.z,RZ.z}, xhi, yhi, zhi));
        a3 = __builtin_elementwise_min(a3, d2p((v2f){RX.w,RX.w},(v2f){RY.w,RY.w},(v2f){RZ.w,RZ.w}, xlo, ylo, zlo));
        a3 = __builtin_elementwise_min(a3, d2p((v2f){RX.w,RX.w},(v2f){RY.w,RY.w},(v2f){RZ.w,RZ.w}, xhi, yhi, zhi));
    }
    const float m0 = fminf(a0.x, a0.y);
    const float m1 = fminf(a1.x, a1.y);
    const float m2 = fminf(a2.x, a2.y);
    const float m3 = fminf(a3.x, a3.y);
    float bmn = fminf(fminf(m0, m1), fminf(m2, m3));
    #pragma unroll
    for (int off = 8; off; off >>= 1) bmn = fminf(bmn, __shfl_xor(bmn, off, 64));
    const unsigned g0 = (unsigned)(__ballot(m0 == bmn) >> gsh) & 0xFFFFu;
    const unsigned g1 = (unsigned)(__ballot(m1 == bmn) >> gsh) & 0xFFFFu;
    const unsigned g2 = (unsigned)(__ballot(m2 == bmn) >> gsh) & 0xFFFFu;
    const unsigned g3 = (unsigned)(__ballot(m3 == bmn) >> gsh) & 0xFFFFu;
    const int t1 = __builtin_ctz(g0 | g1 | g2 | g3);
    const int s1 = (g0 >> t1) & 1 ? 0 : (g1 >> t1) & 1 ? 1 : (g2 >> t1) & 1 ? 2 : 3;
    const float v1x = __shfl(sel4(s1, RX.x, RX.y, RX.z, RX.w), gsh + t1, 64);
    const float v1y = __shfl(sel4(s1, RY.x, RY.y, RY.z, RY.w), gsh + t1, 64);
    const float v1z = __shfl(sel4(s1, RZ.x, RZ.y, RZ.z, RZ.w), gsh + t1, 64);
    const float d0 = d2f(v1x, v1y, v1z, CX.x, CY.x, CZ.x);
    const float d1 = d2f(v1x, v1y, v1z, CX.y, CY.y, CZ.y);
    const float d2_ = d2f(v1x, v1y, v1z, CX.z, CY.z, CZ.z);
    const float d3 = d2f(v1x, v1y, v1z, CX.w, CY.w, CZ.w);
    const unsigned h0 = (unsigned)(__ballot(d0 == bmn) >> gsh) & 0xFFFFu;
    const unsigned h1 = (unsigned)(__ballot(d1 == bmn) >> gsh) & 0xFFFFu;
    const unsigned h2 = (unsigned)(__ballot(d2_ == bmn) >> gsh) & 0xFFFFu;
    const unsigned h3 = (unsigned)(__ballot(d3 == bmn) >> gsh) & 0xFFFFu;
    const int t2 = __builtin_ctz(h0 | h1 | h2 | h3);
    const int s2 = (h0 >> t2) & 1 ? 0 : (h1 >> t2) & 1 ? 1 : (h2 >> t2) & 1 ? 2 : 3;
    const float v2x = __shfl(sel4(s2, CX.x, CX.y, CX.z, CX.w), gsh + t2, 64);
    const float v2y = __shfl(sel4(s2, CY.x, CY.y, CY.z, CY.w), gsh + t2, 64);
    const float v2z = __shfl(sel4(s2, CZ.x, CZ.y, CZ.z, CZ.w), gsh + t2, 64);
    float dx = v1x - v2x, dy = v1y - v2y, dz = v1z - v2z;
    const float lend = sqrtf(dx * dx + dy * dy + dz * dz);
    if (lend > 0.f) { dx /= lend; dy /= lend; dz /= lend; }
    if (e < E) {
        float* orow = out + (size_t)e * 19;
        float o;
        if (t < 3)       o = sel3(t,     v1x, v1y, v1z);
        else if (t < 6)  o = sel3(t - 3, v2x, v2y, v2z);
        else if (t < 9)  o = sel3(t - 6, dx, dy, dz);
        else if (t == 9) o = lend;
        else {
            const int k = t - 10;
            o = sel3(k / 3, dx, dy, dz) * sel3(k % 3, dx, dy, dz);
        }
        orow[t] = o;
        if (t < 3) {
            const int k = t + 6;
            orow[16 + t] = sel3(k / 3, dx, dy, dz) * sel3(k % 3, dx, dy, dz);
        }
    }
}

extern "C" void kernel_launch(void* const* d_in, const int* in_sizes, int n_in,
                              void* d_out, int out_size, void* d_ws, size_t ws_size,
                              hipStream_t stream) {
    const float* data   = (const float*)d_in[0];
    const int*   clusts = (const int*)d_in[1];
    const int*   eidx   = (const int*)d_in[2];
    float*       out    = (float*)d_out;
    const int E = in_sizes[2] / 2;            // edge_index is (2, E)
    const int C = in_sizes[1] / 64;           // clusts is (C, 64)
    const size_t tbytes = (size_t)C * 192 * sizeof(float);

    if (ws_size >= tbytes) {
        float* T = (float*)d_ws;
        build_table_kernel<<<(C + 3) / 4, 256, 0, stream>>>(data, clusts, T, C);
        clustgeo_scan_kernel<<<(E + 15) / 16, 256, 0, stream>>>(T, eidx, out, E);
    } else {
        clustgeo_edge_fallback<<<(E + 15) / 16, 256, 0, stream>>>(data, clusts, eidx, out, E);
    }
}